// Round 8
// baseline (441.752 us; speedup 1.0000x reference)
//
#include <hip/hip_runtime.h>
#include <math.h>

#define VOCAB 4096
#define EMBED 64
#define OBSD  128
#define HIDD  512
#define BNR   4096        // batch rows (1024*4)
#define ZR    65536       // token rows (BNR*16)
#define ZD    1024        // 16*EMBED
#define NCHUNK 4
#define CHSZ  (VOCAB / NCHUNK)   // 1024 codes per chunk
#define TCODES 64                // codes per LDS tile
#define NTILES (CHSZ / TCODES)   // 16 tiles per chunk

// dist now computes APPROX scores (hi-only f16 MFMA): ε = |zlo·c + zhi·clo|,
// rms ≈ 1.7e-3 scaled. Margin 0.02 ≈ 12σ_ε; every row with top-2 gap < margin
// gets an exact fp64 rescan. Rescue rate ≈ 1.8% (~1150 rows).
#define MARGIN_SCALED 2.0e-2f

// LDS layout strides (halfs), padded: slice stride 136 (not 128) to break
// power-of-2 bank alignment between k-slices.
#define SSTR 136
#define GSTR (8 * SSTR)          // 1088 halfs per 16-code group
#define TYPSZ (4 * GSTR)         // 4352 halfs per tile buffer (hi only)

typedef _Float16 half8  __attribute__((ext_vector_type(8)));
typedef _Float16 half4  __attribute__((ext_vector_type(4)));
typedef short    bf16x8 __attribute__((ext_vector_type(8)));
typedef float    f32x4  __attribute__((ext_vector_type(4)));

__device__ __forceinline__ f32x4 mfma_f16(half8 a, half8 b, f32x4 c){
  return __builtin_amdgcn_mfma_f32_16x16x32_f16(a,b,c,0,0,0);
}
__device__ __forceinline__ f32x4 mfma_bf(bf16x8 a, bf16x8 b, f32x4 c){
  return __builtin_amdgcn_mfma_f32_16x16x32_bf16(a,b,c,0,0,0);
}
__device__ __forceinline__ unsigned short f2bf(float f){
  union{float f; unsigned u;} x; x.f=f;
  unsigned u = x.u + 0x7fffu + ((x.u>>16)&1u);
  return (unsigned short)(u>>16);
}
__device__ __forceinline__ float bf2f(unsigned short h){
  union{unsigned u; float f;} x; x.u = ((unsigned)h)<<16; return x.f;
}
__device__ __forceinline__ void split3(float w, unsigned short& b1,
                                       unsigned short& b2, unsigned short& b3){
  b1 = f2bf(w); float r  = w - bf2f(b1);
  b2 = f2bf(r); float r2 = r - bf2f(b2);
  b3 = f2bf(r2);
}
__device__ __forceinline__ bf16x8 ldbf(const unsigned short* p){
  return *(const bf16x8*)(const void*)p;
}

// ---------- fused prep: cb f16 (hi only) + weight splits/transposes + rcnt zero
__global__ __launch_bounds__(256) void prep_all_kernel(
    const float* __restrict__ cb, _Float16* __restrict__ chi,
    float* __restrict__ bcol,
    const float* __restrict__ ew1, unsigned short* __restrict__ w1t1,
    unsigned short* __restrict__ w1t2, unsigned short* __restrict__ w1t3,
    const float* __restrict__ ew2, unsigned short* __restrict__ w2t1,
    unsigned short* __restrict__ w2t2, unsigned short* __restrict__ w2t3,
    const float* __restrict__ obs, unsigned short* __restrict__ o1,
    unsigned short* __restrict__ o2, unsigned short* __restrict__ o3,
    const float* __restrict__ dw1, unsigned short* __restrict__ d1t,
    const float* __restrict__ dw2, unsigned short* __restrict__ d2t,
    int* __restrict__ rcnt)
{
  const int b = blockIdx.x;
  const int t = threadIdx.x;
  if (b == 0 && t == 0) *rcnt = 0;
  if (b < 16) {
    // codebook: f16 hi (x4096 scale) + (-0.5*||c||^2)*4096
    int j = b * 256 + t;
    double s = 0.0;
    #pragma unroll 8
    for (int d = 0; d < EMBED; ++d) {
      float c = cb[j * EMBED + d];
      s += (double)c * (double)c;
      chi[j * EMBED + d] = (_Float16)(c * 4096.0f);   // pow2 scale exact
    }
    bcol[j] = (float)(-0.5 * s * 4096.0);
  } else if (b < 272) {
    // ew1 [OBSD][HIDD] -> 3-split [HIDD][OBSD]
    int e = (b - 16) * 256 + t;
    int n = e / OBSD, k = e % OBSD;
    split3(ew1[(size_t)k * HIDD + n], w1t1[e], w1t2[e], w1t3[e]);
  } else if (b < 2320) {
    // ew2 [HIDD][ZD] -> 3-split [ZD][HIDD]
    int e = (b - 272) * 256 + t;
    int n = e / HIDD, k = e % HIDD;
    split3(ew2[(size_t)k * ZD + n], w2t1[e], w2t2[e], w2t3[e]);
  } else if (b < 4368) {
    // obs elementwise 3-split
    int e = (b - 2320) * 256 + t;
    split3(obs[e], o1[e], o2[e], o3[e]);
  } else if (b < 6416) {
    // dw1 [ZD][HIDD] -> bf16 [HIDD][ZD]
    int e = (b - 4368) * 256 + t;
    int n = e / ZD, k = e % ZD;
    d1t[e] = f2bf(dw1[(size_t)k * HIDD + n]);
  } else {
    // dw2 [HIDD][OBSD] -> bf16 [OBSD][HIDD]
    int e = (b - 6416) * 256 + t;
    int n = e / HIDD, k = e % HIDD;
    d2t[e] = f2bf(dw2[(size_t)k * OBSD + n]);
  }
}

// ---------- encoder GEMM: bf16 3-split, 6 MFMA passes, per-k-step fp64 drain.
template<bool RELU>
__global__ __launch_bounds__(256) void enc_mfma_kernel(
    const unsigned short* __restrict__ A1, const unsigned short* __restrict__ A2,
    const unsigned short* __restrict__ A3,
    const unsigned short* __restrict__ B1, const unsigned short* __restrict__ B2,
    const unsigned short* __restrict__ B3,
    const float* __restrict__ bias, int M, int N, int K,
    unsigned short* __restrict__ H1, unsigned short* __restrict__ H2,
    unsigned short* __restrict__ H3,
    float* __restrict__ Z, _Float16* __restrict__ Zhi)
{
  const int tid  = threadIdx.x;
  const int wave = tid >> 6;
  const int lane = tid & 63;
  const int l15  = lane & 15;
  const int lg   = lane >> 4;
  const int m0 = blockIdx.x * 64 + (wave >> 1) * 32;
  const int n0 = blockIdx.y * 64 + (wave & 1) * 32;

  double accd[2][2][4] = {};

  for (int k0 = 0; k0 < K; k0 += 32) {
    bf16x8 a1[2], a2[2], a3[2], b1[2], b2[2], b3[2];
    #pragma unroll
    for (int ms = 0; ms < 2; ++ms) {
      size_t base = (size_t)(m0 + ms * 16 + l15) * K + k0 + lg * 8;
      a1[ms] = ldbf(A1 + base); a2[ms] = ldbf(A2 + base); a3[ms] = ldbf(A3 + base);
    }
    #pragma unroll
    for (int ns = 0; ns < 2; ++ns) {
      size_t base = (size_t)(n0 + ns * 16 + l15) * K + k0 + lg * 8;
      b1[ns] = ldbf(B1 + base); b2[ns] = ldbf(B2 + base); b3[ns] = ldbf(B3 + base);
    }
    #pragma unroll
    for (int ms = 0; ms < 2; ++ms)
      #pragma unroll
      for (int ns = 0; ns < 2; ++ns) {
        f32x4 acc = {0.f, 0.f, 0.f, 0.f};
        // smallest terms first, dominant a1*b1 last
        acc = mfma_bf(a1[ms], b3[ns], acc);
        acc = mfma_bf(a2[ms], b2[ns], acc);
        acc = mfma_bf(a3[ms], b1[ns], acc);
        acc = mfma_bf(a1[ms], b2[ns], acc);
        acc = mfma_bf(a2[ms], b1[ns], acc);
        acc = mfma_bf(a1[ms], b1[ns], acc);
        #pragma unroll
        for (int r = 0; r < 4; ++r) accd[ms][ns][r] += (double)acc[r];
      }
  }

  #pragma unroll
  for (int ms = 0; ms < 2; ++ms)
    #pragma unroll
    for (int ns = 0; ns < 2; ++ns)
      #pragma unroll
      for (int r = 0; r < 4; ++r) {
        int row = m0 + ms * 16 + lg * 4 + r;
        int col = n0 + ns * 16 + l15;
        float v = (float)accd[ms][ns][r] + bias[col];
        size_t o = (size_t)row * N + col;
        if constexpr (RELU) {
          v = v > 0.f ? v : 0.f;
          split3(v, H1[o], H2[o], H3[o]);
        } else {
          Z[o] = v;
          Zhi[o] = (_Float16)v;
        }
      }
}

// ---------- decoder GEMM: plain bf16 1-pass MFMA (2%-of-max tolerance)
template<bool RELU, bool OUTBF>
__global__ __launch_bounds__(256) void dec_mfma_kernel(
    const unsigned short* __restrict__ A, const unsigned short* __restrict__ B,
    const float* __restrict__ bias, int M, int N, int K,
    unsigned short* __restrict__ Obf, float* __restrict__ Of)
{
  const int tid  = threadIdx.x;
  const int wave = tid >> 6;
  const int lane = tid & 63;
  const int l15  = lane & 15;
  const int lg   = lane >> 4;
  const int m0 = blockIdx.x * 64 + (wave >> 1) * 32;
  const int n0 = blockIdx.y * 64 + (wave & 1) * 32;

  f32x4 acc[2][2] = {};
  for (int k0 = 0; k0 < K; k0 += 32) {
    bf16x8 a[2], b[2];
    #pragma unroll
    for (int ms = 0; ms < 2; ++ms)
      a[ms] = ldbf(A + (size_t)(m0 + ms * 16 + l15) * K + k0 + lg * 8);
    #pragma unroll
    for (int ns = 0; ns < 2; ++ns)
      b[ns] = ldbf(B + (size_t)(n0 + ns * 16 + l15) * K + k0 + lg * 8);
    #pragma unroll
    for (int ms = 0; ms < 2; ++ms)
      #pragma unroll
      for (int ns = 0; ns < 2; ++ns)
        acc[ms][ns] = mfma_bf(a[ms], b[ns], acc[ms][ns]);
  }
  #pragma unroll
  for (int ms = 0; ms < 2; ++ms)
    #pragma unroll
    for (int ns = 0; ns < 2; ++ns)
      #pragma unroll
      for (int r = 0; r < 4; ++r) {
        int row = m0 + ms * 16 + lg * 4 + r;
        int col = n0 + ns * 16 + l15;
        float v = acc[ms][ns][r] + bias[col];
        if constexpr (RELU) v = v > 0.f ? v : 0.f;
        if constexpr (OUTBF) Obf[(size_t)row * N + col] = f2bf(v);
        else                 Of[(size_t)row * N + col] = v;
      }
}

// ---------- VQ distance: APPROX hi-only f16 MFMA (2 per chain), chunked,
// LDS-staged codebook, 16 waves/block (r7-proven residency). Each wave owns
// 32 rows (2 subtiles); per (grp,s): seed=bcol, 2 MFMA over K=64. Top-2 gap
// tracked on approx scores; merge flags gap<0.02 rows for exact fp64 rescue.
// NOTE: no min-waves clause — a VGPR cap makes the compiler demote the
// loop-invariant z fragments to per-iteration reloads (r3: 2 GB HBM, 3x slower).
__global__ __launch_bounds__(1024) void dist_kernel(
    const _Float16* __restrict__ zhi, const _Float16* __restrict__ chi,
    const float* __restrict__ bcol,
    float2* __restrict__ pb2, int* __restrict__ pidx)
{
  __shared__ _Float16 sh[2][TYPSZ];      // [buf][padded 64-code tile], hi only
  __shared__ float    sbc[CHSZ];

  const int tid  = threadIdx.x;
  const int wave = tid >> 6;
  const int lane = tid & 63;
  const int l15  = lane & 15;
  const int lg   = lane >> 4;
  const int rowW = blockIdx.x * 512 + wave * 32;
  const int ch   = blockIdx.y;

  // z fragments: loop-invariant, stay in VGPRs (2 subtiles x 2 frags x 4 regs)
  half8 ah0[2], ah1[2];
  #pragma unroll
  for (int s = 0; s < 2; ++s) {
    const size_t base = (size_t)(rowW + s * 16 + l15) * EMBED + lg * 8;
    ah0[s] = *(const half8*)(zhi + base);
    ah1[s] = *(const half8*)(zhi + base + 32);
  }

  // staging: 1024 8B-chunks per tile; thread t handles exactly one chunk.
  // chunk c: code = c>>4, rem = c&15, slice = rem>>1, half4-idx = rem&1.
  const _Float16* gsrc = chi + (size_t)ch * CHSZ * EMBED;
  const int code = tid >> 4, rem = tid & 15, sl = rem >> 1, hf = rem & 1;
  const int ld = (code >> 4) * GSTR + sl * SSTR + (code & 15) * 8 + hf * 4;
  const size_t goff = (size_t)code * EMBED + sl * 8 + hf * 4;

  // bcol for this chunk -> LDS
  sbc[tid] = bcol[ch * CHSZ + tid];

  // prologue: stage tile 0 into buf 0
  *(half4*)(&sh[0][ld]) = *(const half4*)(gsrc + goff);
  __syncthreads();

  float best[2][4], second[2][4];
  int   bidx[2][4];
  #pragma unroll
  for (int s = 0; s < 2; ++s)
    #pragma unroll
    for (int r = 0; r < 4; ++r) {
      best[s][r] = -INFINITY; second[s][r] = -INFINITY; bidx[s][r] = 0;
    }

  for (int tile = 0; tile < NTILES; ++tile) {
    const int buf = tile & 1;
    // issue next tile's global load early; written to LDS after the barrier
    half4 v0 = {};
    if (tile + 1 < NTILES)
      v0 = *(const half4*)(gsrc + (size_t)(tile + 1) * (TCODES * EMBED) + goff);

    const _Float16* ph = &sh[buf][0];
    #pragma unroll
    for (int grp = 0; grp < 4; ++grp) {
      const int rb = grp * GSTR + l15 * 8;
      half8 bh0 = *(const half8*)(ph + rb + lg * SSTR);
      half8 bh1 = *(const half8*)(ph + rb + (4 + lg) * SSTR);
      const int cloc = tile * TCODES + grp * 16 + l15;
      const int col  = ch * CHSZ + cloc;
      const float vb = sbc[cloc];
      const f32x4 seed = {vb, vb, vb, vb};     // shared across the 2 s-chains
      #pragma unroll
      for (int s = 0; s < 2; ++s) {
        f32x4 acc = seed;
        acc = mfma_f16(ah0[s], bh0, acc);
        acc = mfma_f16(ah1[s], bh1, acc);
        #pragma unroll
        for (int r = 0; r < 4; ++r) {
          float v = acc[r];
          float sn = __builtin_amdgcn_fmed3f(second[s][r], best[s][r], v);
          bool gt = v > best[s][r];
          best[s][r] = gt ? v : best[s][r];
          bidx[s][r] = gt ? col : bidx[s][r];
          second[s][r] = sn;
        }
      }
    }
    __syncthreads();              // all waves done reading buf^1 (last iter)
    if (tile + 1 < NTILES)
      *(half4*)(&sh[buf ^ 1][ld]) = v0;
    __syncthreads();              // next tile visible
  }

  // reduce (best,second,idx) across the 16 col-lanes (low 4 lane bits)
  #pragma unroll
  for (int m = 1; m <= 8; m <<= 1) {
    #pragma unroll
    for (int s = 0; s < 2; ++s)
      #pragma unroll
      for (int r = 0; r < 4; ++r) {
        float ob = __shfl_xor(best[s][r], m, 64);
        float os = __shfl_xor(second[s][r], m, 64);
        int   oi = __shfl_xor(bidx[s][r], m, 64);
        float mn = fminf(best[s][r], ob);
        second[s][r] = fmaxf(mn, fmaxf(second[s][r], os));
        if (ob > best[s][r]) { best[s][r] = ob; bidx[s][r] = oi; }
      }
  }

  if (l15 == 0) {
    #pragma unroll
    for (int s = 0; s < 2; ++s)
      #pragma unroll
      for (int r = 0; r < 4; ++r) {
        int row = rowW + s * 16 + lg * 4 + r;
        pb2 [(size_t)ch * ZR + row] = make_float2(best[s][r], second[s][r]);
        pidx[(size_t)ch * ZR + row] = bidx[s][r];
      }
  }
}

// ---------- merge chunk partials -> tokens + rescue list (approx-gap margin)
__global__ __launch_bounds__(256) void merge_kernel(
    const float2* __restrict__ pb2, const int* __restrict__ pidx,
    int* __restrict__ tokens, int* __restrict__ rcnt, int* __restrict__ rrows)
{
  int r = blockIdx.x * 256 + threadIdx.x;
  float b = -INFINITY, s = -INFINITY;
  int bi = 0;
  #pragma unroll
  for (int c = 0; c < NCHUNK; ++c) {
    float2 p = pb2[(size_t)c * ZR + r];
    int    i = pidx[(size_t)c * ZR + r];
    if (p.x > b) { s = fmaxf(b, p.y); b = p.x; bi = i; }
    else         { s = fmaxf(s, p.x); }
  }
  tokens[r] = bi;
  if (b - s < MARGIN_SCALED) {
    int p = atomicAdd(rcnt, 1);
    if (p < ZR) rrows[p] = r;
  }
}

// ---------- exact fp64 rescan for ambiguous tokens (correctness anchor)
__global__ __launch_bounds__(256) void rescue_kernel(
    const int* __restrict__ cnt, const int* __restrict__ rows,
    const float* __restrict__ z, const float* __restrict__ cb,
    int* __restrict__ tokens)
{
  __shared__ float  zrow[EMBED];
  __shared__ double sv[256];
  __shared__ int    si[256];
  int n = *cnt; if (n > ZR) n = ZR;
  for (int e = blockIdx.x; e < n; e += gridDim.x) {
    int row = rows[e];
    __syncthreads();
    if (threadIdx.x < EMBED / 4)
      ((float4*)zrow)[threadIdx.x] = ((const float4*)(z + (size_t)row * EMBED))[threadIdx.x];
    __syncthreads();
    double bv = 1e300; int bi = VOCAB;
    for (int j = threadIdx.x; j < VOCAB; j += 256) {
      double d = 0.0;
      #pragma unroll
      for (int k = 0; k < EMBED; ++k) {
        double c = (double)cb[(size_t)j * EMBED + k];
        d += c * (c - 2.0 * (double)zrow[k]);
      }
      if (d < bv || (d == bv && j < bi)) { bv = d; bi = j; }
    }
    sv[threadIdx.x] = bv; si[threadIdx.x] = bi;
    __syncthreads();
    for (int s = 128; s > 0; s >>= 1) {
      if (threadIdx.x < (unsigned)s) {
        double ov = sv[threadIdx.x + s]; int oi = si[threadIdx.x + s];
        if (ov < sv[threadIdx.x] || (ov == sv[threadIdx.x] && oi < si[threadIdx.x])) {
          sv[threadIdx.x] = ov; si[threadIdx.x] = oi;
        }
      }
      __syncthreads();
    }
    if (threadIdx.x == 0) tokens[row] = si[0];
  }
}

// ---------- gather z_q: exact fp32 copy + bf16 copy for the decoder
__global__ __launch_bounds__(256) void gather_kernel(
    const int* __restrict__ tokens, const float* __restrict__ cb,
    float* __restrict__ zq, unsigned short* __restrict__ zqb)
{
  int g = blockIdx.x * 256 + threadIdx.x;            // (row, 16B-part)
  int row = g >> 4;
  int part = g & 15;
  int tok = tokens[row];
  float4 cv = ((const float4*)cb)[tok * 16 + part];
  ((float4*)zq)[g] = cv;
  ushort4 o;
  o.x = f2bf(cv.x); o.y = f2bf(cv.y); o.z = f2bf(cv.z); o.w = f2bf(cv.w);
  ((ushort4*)zqb)[g] = o;
}

extern "C" void kernel_launch(void* const* d_in, const int* in_sizes, int n_in,
                              void* d_out, int out_size, void* d_ws, size_t ws_size,
                              hipStream_t stream)
{
  const float* obs = (const float*)d_in[0];
  const float* ew1 = (const float*)d_in[1];
  const float* eb1 = (const float*)d_in[2];
  const float* ew2 = (const float*)d_in[3];
  const float* eb2 = (const float*)d_in[4];
  const float* dw1 = (const float*)d_in[5];
  const float* db1 = (const float*)d_in[6];
  const float* dw2 = (const float*)d_in[7];
  const float* db2 = (const float*)d_in[8];
  const float* cb  = (const float*)d_in[9];

  float* out_z   = (float*)d_out;                    // [65536][64]
  float* out_zq  = out_z + (size_t)ZR * EMBED;       // [65536][64]
  float* out_rec = out_z + 2 * (size_t)ZR * EMBED;   // [4096][128]

  // h 3-split (3 x 4MB) staged in the (dead-until-gather) out_zq slot
  unsigned short* h1 = (unsigned short*)out_zq;
  unsigned short* h2 = h1 + (size_t)BNR * HIDD;
  unsigned short* h3 = h2 + (size_t)BNR * HIDD;

  char* w = (char*)d_ws;
  _Float16* chi = (_Float16*)w;  w += (size_t)VOCAB * EMBED * 2;  // 512 KB
  float*    bcol = (float*)w;    w += 64 * 1024;                  // 16 KB used
  _Float16* zhi = (_Float16*)w;  w += (size_t)ZR * EMBED * 2;     // 8 MB
  char*     spare = w;           w += (size_t)ZR * EMBED * 2;     // 8 MB (hdec)
  unsigned short* w1t1 = (unsigned short*)w; w += (size_t)HIDD * OBSD * 2;
  unsigned short* w1t2 = (unsigned short*)w; w += (size_t)HIDD * OBSD * 2;
  unsigned short* w1t3 = (unsigned short*)w; w += (size_t)HIDD * OBSD * 2;
  unsigned short* w2t1 = (unsigned short*)w; w += (size_t)ZD * HIDD * 2;
  unsigned short* w2t2 = (unsigned short*)w; w += (size_t)ZD * HIDD * 2;
  unsigned short* w2t3 = (unsigned short*)w; w += (size_t)ZD * HIDD * 2;
  unsigned short* d1t  = (unsigned short*)w; w += (size_t)HIDD * ZD * 2;
  unsigned short* d2t  = (unsigned short*)w; w += (size_t)OBSD * HIDD * 2;
  int* tokens = (int*)w;  w += (size_t)ZR * 4;
  int* rrows  = (int*)w;  w += (size_t)ZR * 4;
  int* rcnt   = (int*)w;  w += 64;
  float2* pb2 = (float2*)w; w += (size_t)NCHUNK * ZR * 8;         // 2 MB
  int*   pidx = (int*)w;    w += (size_t)NCHUNK * ZR * 4;         // 1 MB

  // overlays (dead-time disjoint):
  // obs 3-split lives [prep..enc1]; zhi written by enc2 (after enc1)
  unsigned short* o1 = (unsigned short*)zhi;
  unsigned short* o2 = o1 + (size_t)BNR * OBSD;
  unsigned short* o3 = o2 + (size_t)BNR * OBSD;
  // zq bf16 lives [gather..dec1], zhi dead after dist
  unsigned short* zqb  = (unsigned short*)zhi;
  // dec hidden lives [dec1..dec2] in the spare slot
  unsigned short* hdec = (unsigned short*)spare;

  prep_all_kernel<<<6672, 256, 0, stream>>>(
      cb, chi, bcol,
      ew1, w1t1, w1t2, w1t3,
      ew2, w2t1, w2t2, w2t3,
      obs, o1, o2, o3,
      dw1, d1t, dw2, d2t, rcnt);

  // encoder (bf16 3-split MFMA + fp64 drain => np-fp32-grade z)
  enc_mfma_kernel<true><<<dim3(BNR / 64, HIDD / 64), 256, 0, stream>>>(
      o1, o2, o3, w1t1, w1t2, w1t3, eb1, BNR, HIDD, OBSD,
      h1, h2, h3, nullptr, nullptr);
  enc_mfma_kernel<false><<<dim3(BNR / 64, ZD / 64), 256, 0, stream>>>(
      h1, h2, h3, w2t1, w2t2, w2t3, eb2, BNR, ZD, HIDD,
      nullptr, nullptr, nullptr, out_z, zhi);

  dist_kernel<<<dim3(ZR / 512, NCHUNK), 1024, 0, stream>>>(
      zhi, chi, bcol, pb2, pidx);
  merge_kernel<<<ZR / 256, 256, 0, stream>>>(pb2, pidx, tokens, rcnt, rrows);
  rescue_kernel<<<512, 256, 0, stream>>>(rcnt, rrows, out_z, cb, tokens);
  gather_kernel<<<(ZR * 16) / 256, 256, 0, stream>>>(tokens, cb, out_zq, zqb);

  // decoder (bf16 1-pass MFMA)
  dec_mfma_kernel<true, true><<<dim3(BNR / 64, HIDD / 64), 256, 0, stream>>>(
      zqb, d1t, db1, BNR, HIDD, ZD, hdec, nullptr);
  dec_mfma_kernel<false, false><<<dim3(BNR / 64, OBSD / 64), 256, 0, stream>>>(
      hdec, d2t, db2, BNR, OBSD, HIDD, nullptr, out_rec);
}

// Round 9
// 294.619 us; speedup vs baseline: 1.4994x; 1.4994x over previous
//
#include <hip/hip_runtime.h>
#include <math.h>

#define VOCAB 4096
#define EMBED 64
#define OBSD  128
#define HIDD  512
#define BNR   4096        // batch rows (1024*4)
#define ZR    65536       // token rows (BNR*16)
#define ZD    1024        // 16*EMBED
#define NCHUNK 4
#define CHSZ  (VOCAB / NCHUNK)   // 1024 codes per chunk
#define TCODES 64                // codes per LDS tile
#define NTILES (CHSZ / TCODES)   // 16 tiles per chunk

// dist computes z-split scores (zhi+zlo vs unsplit c): ε = |z·Δc| ≈ 3.5e-4 rms
// scaled. Margin 4e-3 ≈ 7σ of gap noise; rows with approx top-2 gap < margin
// get an exact fp64 rescan (rescue v2, batched).
#define MARGIN_SCALED 4.0e-3f

// LDS layout strides (halfs), padded: slice stride 136 (not 128) to break
// power-of-2 bank alignment between k-slices.
#define SSTR 136
#define GSTR (8 * SSTR)          // 1088 halfs per 16-code group
#define TYPSZ (4 * GSTR)         // 4352 halfs per tile buffer (hi only)

#define RB 8                     // rescue rows per batch

typedef _Float16 half8  __attribute__((ext_vector_type(8)));
typedef _Float16 half4  __attribute__((ext_vector_type(4)));
typedef short    bf16x8 __attribute__((ext_vector_type(8)));
typedef float    f32x4  __attribute__((ext_vector_type(4)));

__device__ __forceinline__ f32x4 mfma_f16(half8 a, half8 b, f32x4 c){
  return __builtin_amdgcn_mfma_f32_16x16x32_f16(a,b,c,0,0,0);
}
__device__ __forceinline__ f32x4 mfma_bf(bf16x8 a, bf16x8 b, f32x4 c){
  return __builtin_amdgcn_mfma_f32_16x16x32_bf16(a,b,c,0,0,0);
}
__device__ __forceinline__ unsigned short f2bf(float f){
  union{float f; unsigned u;} x; x.f=f;
  unsigned u = x.u + 0x7fffu + ((x.u>>16)&1u);
  return (unsigned short)(u>>16);
}
__device__ __forceinline__ float bf2f(unsigned short h){
  union{unsigned u; float f;} x; x.u = ((unsigned)h)<<16; return x.f;
}
__device__ __forceinline__ void split3(float w, unsigned short& b1,
                                       unsigned short& b2, unsigned short& b3){
  b1 = f2bf(w); float r  = w - bf2f(b1);
  b2 = f2bf(r); float r2 = r - bf2f(b2);
  b3 = f2bf(r2);
}
__device__ __forceinline__ bf16x8 ldbf(const unsigned short* p){
  return *(const bf16x8*)(const void*)p;
}

// ---------- fused prep: cb f16 + cbT + fp64 bias + weight splits + rcnt zero
__global__ __launch_bounds__(256) void prep_all_kernel(
    const float* __restrict__ cb, _Float16* __restrict__ chi,
    float* __restrict__ bcol, double* __restrict__ bcold,
    float* __restrict__ cbT,
    const float* __restrict__ ew1, unsigned short* __restrict__ w1t1,
    unsigned short* __restrict__ w1t2, unsigned short* __restrict__ w1t3,
    const float* __restrict__ ew2, unsigned short* __restrict__ w2t1,
    unsigned short* __restrict__ w2t2, unsigned short* __restrict__ w2t3,
    const float* __restrict__ obs, unsigned short* __restrict__ o1,
    unsigned short* __restrict__ o2, unsigned short* __restrict__ o3,
    const float* __restrict__ dw1, unsigned short* __restrict__ d1t,
    const float* __restrict__ dw2, unsigned short* __restrict__ d2t,
    int* __restrict__ rcnt)
{
  const int b = blockIdx.x;
  const int t = threadIdx.x;
  if (b == 0 && t == 0) *rcnt = 0;
  if (b < 16) {
    // codebook: f16 (x4096 scale) + transpose fp32 + (-0.5||c||^2)*4096 (f32+f64)
    int j = b * 256 + t;
    double s = 0.0;
    #pragma unroll 8
    for (int d = 0; d < EMBED; ++d) {
      float c = cb[j * EMBED + d];
      s += (double)c * (double)c;
      chi[j * EMBED + d] = (_Float16)(c * 4096.0f);   // pow2 scale exact
      cbT[(size_t)d * VOCAB + j] = c;                 // coalesced write
    }
    double bd = -0.5 * s * 4096.0;
    bcold[j] = bd;
    bcol[j] = (float)bd;
  } else if (b < 272) {
    // ew1 [OBSD][HIDD] -> 3-split [HIDD][OBSD]
    int e = (b - 16) * 256 + t;
    int n = e / OBSD, k = e % OBSD;
    split3(ew1[(size_t)k * HIDD + n], w1t1[e], w1t2[e], w1t3[e]);
  } else if (b < 2320) {
    // ew2 [HIDD][ZD] -> 3-split [ZD][HIDD]
    int e = (b - 272) * 256 + t;
    int n = e / HIDD, k = e % HIDD;
    split3(ew2[(size_t)k * ZD + n], w2t1[e], w2t2[e], w2t3[e]);
  } else if (b < 4368) {
    // obs elementwise 3-split
    int e = (b - 2320) * 256 + t;
    split3(obs[e], o1[e], o2[e], o3[e]);
  } else if (b < 6416) {
    // dw1 [ZD][HIDD] -> bf16 [HIDD][ZD]
    int e = (b - 4368) * 256 + t;
    int n = e / ZD, k = e % ZD;
    d1t[e] = f2bf(dw1[(size_t)k * HIDD + n]);
  } else {
    // dw2 [HIDD][OBSD] -> bf16 [OBSD][HIDD]
    int e = (b - 6416) * 256 + t;
    int n = e / HIDD, k = e % HIDD;
    d2t[e] = f2bf(dw2[(size_t)k * OBSD + n]);
  }
}

// ---------- encoder GEMM: bf16 3-split, 6 MFMA passes, per-k-step fp64 drain.
template<bool RELU>
__global__ __launch_bounds__(256) void enc_mfma_kernel(
    const unsigned short* __restrict__ A1, const unsigned short* __restrict__ A2,
    const unsigned short* __restrict__ A3,
    const unsigned short* __restrict__ B1, const unsigned short* __restrict__ B2,
    const unsigned short* __restrict__ B3,
    const float* __restrict__ bias, int M, int N, int K,
    unsigned short* __restrict__ H1, unsigned short* __restrict__ H2,
    unsigned short* __restrict__ H3,
    float* __restrict__ Z, _Float16* __restrict__ Zhi, _Float16* __restrict__ Zlo)
{
  const int tid  = threadIdx.x;
  const int wave = tid >> 6;
  const int lane = tid & 63;
  const int l15  = lane & 15;
  const int lg   = lane >> 4;
  const int m0 = blockIdx.x * 64 + (wave >> 1) * 32;
  const int n0 = blockIdx.y * 64 + (wave & 1) * 32;

  double accd[2][2][4] = {};

  for (int k0 = 0; k0 < K; k0 += 32) {
    bf16x8 a1[2], a2[2], a3[2], b1[2], b2[2], b3[2];
    #pragma unroll
    for (int ms = 0; ms < 2; ++ms) {
      size_t base = (size_t)(m0 + ms * 16 + l15) * K + k0 + lg * 8;
      a1[ms] = ldbf(A1 + base); a2[ms] = ldbf(A2 + base); a3[ms] = ldbf(A3 + base);
    }
    #pragma unroll
    for (int ns = 0; ns < 2; ++ns) {
      size_t base = (size_t)(n0 + ns * 16 + l15) * K + k0 + lg * 8;
      b1[ns] = ldbf(B1 + base); b2[ns] = ldbf(B2 + base); b3[ns] = ldbf(B3 + base);
    }
    #pragma unroll
    for (int ms = 0; ms < 2; ++ms)
      #pragma unroll
      for (int ns = 0; ns < 2; ++ns) {
        f32x4 acc = {0.f, 0.f, 0.f, 0.f};
        // smallest terms first, dominant a1*b1 last
        acc = mfma_bf(a1[ms], b3[ns], acc);
        acc = mfma_bf(a2[ms], b2[ns], acc);
        acc = mfma_bf(a3[ms], b1[ns], acc);
        acc = mfma_bf(a1[ms], b2[ns], acc);
        acc = mfma_bf(a2[ms], b1[ns], acc);
        acc = mfma_bf(a1[ms], b1[ns], acc);
        #pragma unroll
        for (int r = 0; r < 4; ++r) accd[ms][ns][r] += (double)acc[r];
      }
  }

  #pragma unroll
  for (int ms = 0; ms < 2; ++ms)
    #pragma unroll
    for (int ns = 0; ns < 2; ++ns)
      #pragma unroll
      for (int r = 0; r < 4; ++r) {
        int row = m0 + ms * 16 + lg * 4 + r;
        int col = n0 + ns * 16 + l15;
        float v = (float)accd[ms][ns][r] + bias[col];
        size_t o = (size_t)row * N + col;
        if constexpr (RELU) {
          v = v > 0.f ? v : 0.f;
          split3(v, H1[o], H2[o], H3[o]);
        } else {
          Z[o] = v;
          _Float16 hi = (_Float16)v;
          Zhi[o] = hi;
          Zlo[o] = (_Float16)(v - (float)hi);
        }
      }
}

// ---------- decoder GEMM: plain bf16 1-pass MFMA (2%-of-max tolerance)
template<bool RELU, bool OUTBF>
__global__ __launch_bounds__(256) void dec_mfma_kernel(
    const unsigned short* __restrict__ A, const unsigned short* __restrict__ B,
    const float* __restrict__ bias, int M, int N, int K,
    unsigned short* __restrict__ Obf, float* __restrict__ Of)
{
  const int tid  = threadIdx.x;
  const int wave = tid >> 6;
  const int lane = tid & 63;
  const int l15  = lane & 15;
  const int lg   = lane >> 4;
  const int m0 = blockIdx.x * 64 + (wave >> 1) * 32;
  const int n0 = blockIdx.y * 64 + (wave & 1) * 32;

  f32x4 acc[2][2] = {};
  for (int k0 = 0; k0 < K; k0 += 32) {
    bf16x8 a[2], b[2];
    #pragma unroll
    for (int ms = 0; ms < 2; ++ms)
      a[ms] = ldbf(A + (size_t)(m0 + ms * 16 + l15) * K + k0 + lg * 8);
    #pragma unroll
    for (int ns = 0; ns < 2; ++ns)
      b[ns] = ldbf(B + (size_t)(n0 + ns * 16 + l15) * K + k0 + lg * 8);
    #pragma unroll
    for (int ms = 0; ms < 2; ++ms)
      #pragma unroll
      for (int ns = 0; ns < 2; ++ns)
        acc[ms][ns] = mfma_bf(a[ms], b[ns], acc[ms][ns]);
  }
  #pragma unroll
  for (int ms = 0; ms < 2; ++ms)
    #pragma unroll
    for (int ns = 0; ns < 2; ++ns)
      #pragma unroll
      for (int r = 0; r < 4; ++r) {
        int row = m0 + ms * 16 + lg * 4 + r;
        int col = n0 + ns * 16 + l15;
        float v = acc[ms][ns][r] + bias[col];
        if constexpr (RELU) v = v > 0.f ? v : 0.f;
        if constexpr (OUTBF) Obf[(size_t)row * N + col] = f2bf(v);
        else                 Of[(size_t)row * N + col] = v;
      }
}

// ---------- VQ distance: z-split (zhi+zlo) vs unsplit c — 4-MFMA chain.
// Chunked, LDS-staged codebook (hi only), 16 waves/block (r7-proven residency).
// Each wave owns 32 rows (2 subtiles); chain seeded with bcol, small terms
// (zlo) first. Top-2 gap on approx scores; merge flags gap<4e-3 for fp64 rescue.
// NOTE: no min-waves clause — a VGPR cap makes the compiler demote the
// loop-invariant z fragments to per-iteration reloads (r3: 2 GB HBM, 3x slower).
__global__ __launch_bounds__(1024) void dist_kernel(
    const _Float16* __restrict__ zhi, const _Float16* __restrict__ zlo,
    const _Float16* __restrict__ chi, const float* __restrict__ bcol,
    float2* __restrict__ pb2, int* __restrict__ pidx)
{
  __shared__ _Float16 sh[2][TYPSZ];      // [buf][padded 64-code tile]
  __shared__ float    sbc[CHSZ];

  const int tid  = threadIdx.x;
  const int wave = tid >> 6;
  const int lane = tid & 63;
  const int l15  = lane & 15;
  const int lg   = lane >> 4;
  const int rowW = blockIdx.x * 512 + wave * 32;
  const int ch   = blockIdx.y;

  // z fragments: loop-invariant, stay in VGPRs
  half8 ah0[2], ah1[2], al0[2], al1[2];
  #pragma unroll
  for (int s = 0; s < 2; ++s) {
    const size_t base = (size_t)(rowW + s * 16 + l15) * EMBED + lg * 8;
    ah0[s] = *(const half8*)(zhi + base);
    ah1[s] = *(const half8*)(zhi + base + 32);
    al0[s] = *(const half8*)(zlo + base);
    al1[s] = *(const half8*)(zlo + base + 32);
  }

  // staging: 1024 8B-chunks per tile; thread t handles exactly one chunk.
  const _Float16* gsrc = chi + (size_t)ch * CHSZ * EMBED;
  const int code = tid >> 4, rem = tid & 15, sl = rem >> 1, hf = rem & 1;
  const int ld = (code >> 4) * GSTR + sl * SSTR + (code & 15) * 8 + hf * 4;
  const size_t goff = (size_t)code * EMBED + sl * 8 + hf * 4;

  sbc[tid] = bcol[ch * CHSZ + tid];

  *(half4*)(&sh[0][ld]) = *(const half4*)(gsrc + goff);
  __syncthreads();

  float best[2][4], second[2][4];
  int   bidx[2][4];
  #pragma unroll
  for (int s = 0; s < 2; ++s)
    #pragma unroll
    for (int r = 0; r < 4; ++r) {
      best[s][r] = -INFINITY; second[s][r] = -INFINITY; bidx[s][r] = 0;
    }

  for (int tile = 0; tile < NTILES; ++tile) {
    const int buf = tile & 1;
    half4 v0 = {};
    if (tile + 1 < NTILES)
      v0 = *(const half4*)(gsrc + (size_t)(tile + 1) * (TCODES * EMBED) + goff);

    const _Float16* ph = &sh[buf][0];
    #pragma unroll
    for (int grp = 0; grp < 4; ++grp) {
      const int rb = grp * GSTR + l15 * 8;
      half8 bh0 = *(const half8*)(ph + rb + lg * SSTR);
      half8 bh1 = *(const half8*)(ph + rb + (4 + lg) * SSTR);
      const int cloc = tile * TCODES + grp * 16 + l15;
      const int col  = ch * CHSZ + cloc;
      const float vb = sbc[cloc];
      const f32x4 seed = {vb, vb, vb, vb};
      #pragma unroll
      for (int s = 0; s < 2; ++s) {
        // small (zlo) terms first, dominant zhi last
        f32x4 acc = seed;
        acc = mfma_f16(al0[s], bh0, acc);
        acc = mfma_f16(al1[s], bh1, acc);
        acc = mfma_f16(ah0[s], bh0, acc);
        acc = mfma_f16(ah1[s], bh1, acc);
        #pragma unroll
        for (int r = 0; r < 4; ++r) {
          float v = acc[r];
          float sn = __builtin_amdgcn_fmed3f(second[s][r], best[s][r], v);
          bool gt = v > best[s][r];
          best[s][r] = gt ? v : best[s][r];
          bidx[s][r] = gt ? col : bidx[s][r];
          second[s][r] = sn;
        }
      }
    }
    __syncthreads();
    if (tile + 1 < NTILES)
      *(half4*)(&sh[buf ^ 1][ld]) = v0;
    __syncthreads();
  }

  #pragma unroll
  for (int m = 1; m <= 8; m <<= 1) {
    #pragma unroll
    for (int s = 0; s < 2; ++s)
      #pragma unroll
      for (int r = 0; r < 4; ++r) {
        float ob = __shfl_xor(best[s][r], m, 64);
        float os = __shfl_xor(second[s][r], m, 64);
        int   oi = __shfl_xor(bidx[s][r], m, 64);
        float mn = fminf(best[s][r], ob);
        second[s][r] = fmaxf(mn, fmaxf(second[s][r], os));
        if (ob > best[s][r]) { best[s][r] = ob; bidx[s][r] = oi; }
      }
  }

  if (l15 == 0) {
    #pragma unroll
    for (int s = 0; s < 2; ++s)
      #pragma unroll
      for (int r = 0; r < 4; ++r) {
        int row = rowW + s * 16 + lg * 4 + r;
        pb2 [(size_t)ch * ZR + row] = make_float2(best[s][r], second[s][r]);
        pidx[(size_t)ch * ZR + row] = bidx[s][r];
      }
  }
}

// ---------- merge chunk partials -> tokens + rescue list
__global__ __launch_bounds__(256) void merge_kernel(
    const float2* __restrict__ pb2, const int* __restrict__ pidx,
    int* __restrict__ tokens, int* __restrict__ rcnt, int* __restrict__ rrows)
{
  int r = blockIdx.x * 256 + threadIdx.x;
  float b = -INFINITY, s = -INFINITY;
  int bi = 0;
  #pragma unroll
  for (int c = 0; c < NCHUNK; ++c) {
    float2 p = pb2[(size_t)c * ZR + r];
    int    i = pidx[(size_t)c * ZR + r];
    if (p.x > b) { s = fmaxf(b, p.y); b = p.x; bi = i; }
    else         { s = fmaxf(s, p.x); }
  }
  tokens[r] = bi;
  if (b - s < MARGIN_SCALED) {
    int p = atomicAdd(rcnt, 1);
    if (p < ZR) rrows[p] = r;
  }
}

// ---------- rescue v2: exact fp64 rescan, batched (r8 post-mortem: v1 was
// 1 row/block, uncoalesced, latency-bound at ~11 µs/row). Here: 8 rows/batch,
// 512 thr; each thread owns 8 codes x all 8 rows (8 independent fp64 chains),
// coalesced cbT reads, LDS-broadcast z, shuffle+LDS reduction.
__global__ __launch_bounds__(512) void rescue_kernel(
    const int* __restrict__ cnt, const int* __restrict__ rows,
    const float* __restrict__ z, const float* __restrict__ cbT,
    const double* __restrict__ bcold, int* __restrict__ tokens)
{
  __shared__ double zl[RB][EMBED];     // 4 KB, reads are lane-broadcast
  __shared__ int    ridx[RB];
  __shared__ double swv[8][RB];
  __shared__ int    swi[8][RB];

  int n = *cnt; if (n > ZR) n = ZR;
  int nb = (n + RB - 1) / RB;
  const int tid = threadIdx.x;

  for (int batch = blockIdx.x; batch < nb; batch += gridDim.x) {
    __syncthreads();                   // protect zl/ridx reuse across batches
    if (tid < RB) {
      int e = batch * RB + tid;
      ridx[tid] = (e < n) ? rows[e] : -1;
    }
    __syncthreads();
    {
      int r = tid >> 6, k = tid & 63;  // 512 threads = 8x64 exactly
      int rr = ridx[r];
      zl[r][k] = (rr >= 0) ? (double)z[(size_t)rr * EMBED + k] : 0.0;
    }
    __syncthreads();

    double best[RB]; int bidx[RB];
    #pragma unroll
    for (int r = 0; r < RB; ++r) { best[r] = -1.0e300; bidx[r] = 0; }

    for (int c = 0; c < VOCAB / 512; ++c) {
      const int j = c * 512 + tid;     // adjacent lanes -> adjacent j (coalesced)
      double acc[RB] = {};
      #pragma unroll 16
      for (int k = 0; k < EMBED; ++k) {
        double cd = (double)cbT[(size_t)k * VOCAB + j];
        #pragma unroll
        for (int r = 0; r < RB; ++r)
          acc[r] = fma(cd, zl[r][k], acc[r]);
      }
      const double bc = bcold[j];
      #pragma unroll
      for (int r = 0; r < RB; ++r) {
        double s = 4096.0 * acc[r] + bc;
        if (s > best[r]) { best[r] = s; bidx[r] = j; }  // ascending j: ties keep lowest
      }
    }

    #pragma unroll
    for (int m = 1; m < 64; m <<= 1) {
      #pragma unroll
      for (int r = 0; r < RB; ++r) {
        double ov = __shfl_xor(best[r], m, 64);
        int    oi = __shfl_xor(bidx[r], m, 64);
        if (ov > best[r] || (ov == best[r] && oi < bidx[r])) {
          best[r] = ov; bidx[r] = oi;
        }
      }
    }
    const int wv = tid >> 6, ln = tid & 63;
    if (ln == 0)
      #pragma unroll
      for (int r = 0; r < RB; ++r) { swv[wv][r] = best[r]; swi[wv][r] = bidx[r]; }
    __syncthreads();
    if (tid < RB) {
      int r = tid;
      double bv = swv[0][r]; int bi = swi[0][r];
      #pragma unroll
      for (int w2 = 1; w2 < 8; ++w2) {
        double ov = swv[w2][r]; int oi = swi[w2][r];
        if (ov > bv || (ov == bv && oi < bi)) { bv = ov; bi = oi; }
      }
      if (ridx[r] >= 0) tokens[ridx[r]] = bi;
    }
  }
}

// ---------- gather z_q: exact fp32 copy + bf16 copy for the decoder
__global__ __launch_bounds__(256) void gather_kernel(
    const int* __restrict__ tokens, const float* __restrict__ cb,
    float* __restrict__ zq, unsigned short* __restrict__ zqb)
{
  int g = blockIdx.x * 256 + threadIdx.x;            // (row, 16B-part)
  int row = g >> 4;
  int part = g & 15;
  int tok = tokens[row];
  float4 cv = ((const float4*)cb)[tok * 16 + part];
  ((float4*)zq)[g] = cv;
  ushort4 o;
  o.x = f2bf(cv.x); o.y = f2bf(cv.y); o.z = f2bf(cv.z); o.w = f2bf(cv.w);
  ((ushort4*)zqb)[g] = o;
}

extern "C" void kernel_launch(void* const* d_in, const int* in_sizes, int n_in,
                              void* d_out, int out_size, void* d_ws, size_t ws_size,
                              hipStream_t stream)
{
  const float* obs = (const float*)d_in[0];
  const float* ew1 = (const float*)d_in[1];
  const float* eb1 = (const float*)d_in[2];
  const float* ew2 = (const float*)d_in[3];
  const float* eb2 = (const float*)d_in[4];
  const float* dw1 = (const float*)d_in[5];
  const float* db1 = (const float*)d_in[6];
  const float* dw2 = (const float*)d_in[7];
  const float* db2 = (const float*)d_in[8];
  const float* cb  = (const float*)d_in[9];

  float* out_z   = (float*)d_out;                    // [65536][64]
  float* out_zq  = out_z + (size_t)ZR * EMBED;       // [65536][64]
  float* out_rec = out_z + 2 * (size_t)ZR * EMBED;   // [4096][128]

  // h 3-split (3 x 4MB) staged in the (dead-until-gather) out_zq slot
  unsigned short* h1 = (unsigned short*)out_zq;
  unsigned short* h2 = h1 + (size_t)BNR * HIDD;
  unsigned short* h3 = h2 + (size_t)BNR * HIDD;

  char* w = (char*)d_ws;
  _Float16* chi  = (_Float16*)w; w += (size_t)VOCAB * EMBED * 2;  // 512 KB
  float*    bcol = (float*)w;    w += 64 * 1024;                  // 16 KB used
  double*   bcold = (double*)w;  w += 64 * 1024;                  // 32 KB used
  float*    cbT  = (float*)w;    w += (size_t)VOCAB * EMBED * 4;  // 1 MB
  _Float16* zhi  = (_Float16*)w; w += (size_t)ZR * EMBED * 2;     // 8 MB
  _Float16* zlo  = (_Float16*)w; w += (size_t)ZR * EMBED * 2;     // 8 MB
  unsigned short* w1t1 = (unsigned short*)w; w += (size_t)HIDD * OBSD * 2;
  unsigned short* w1t2 = (unsigned short*)w; w += (size_t)HIDD * OBSD * 2;
  unsigned short* w1t3 = (unsigned short*)w; w += (size_t)HIDD * OBSD * 2;
  unsigned short* w2t1 = (unsigned short*)w; w += (size_t)ZD * HIDD * 2;
  unsigned short* w2t2 = (unsigned short*)w; w += (size_t)ZD * HIDD * 2;
  unsigned short* w2t3 = (unsigned short*)w; w += (size_t)ZD * HIDD * 2;
  unsigned short* d1t  = (unsigned short*)w; w += (size_t)HIDD * ZD * 2;
  unsigned short* d2t  = (unsigned short*)w; w += (size_t)OBSD * HIDD * 2;
  int* tokens = (int*)w;  w += (size_t)ZR * 4;
  int* rrows  = (int*)w;  w += (size_t)ZR * 4;
  int* rcnt   = (int*)w;  w += 64;
  float2* pb2 = (float2*)w; w += (size_t)NCHUNK * ZR * 8;         // 2 MB
  int*   pidx = (int*)w;    w += (size_t)NCHUNK * ZR * 4;         // 1 MB

  // overlays (dead-time disjoint):
  // obs 3-split lives [prep..enc1]; zhi/zlo written by enc2 (after enc1)
  unsigned short* o1 = (unsigned short*)zhi;
  unsigned short* o2 = o1 + (size_t)BNR * OBSD;
  unsigned short* o3 = o2 + (size_t)BNR * OBSD;
  // zq bf16 lives [gather..dec1], zhi dead after dist
  unsigned short* zqb  = (unsigned short*)zhi;
  // dec hidden lives [dec1..dec2], zlo dead after dist
  unsigned short* hdec = (unsigned short*)zlo;

  prep_all_kernel<<<6672, 256, 0, stream>>>(
      cb, chi, bcol, bcold, cbT,
      ew1, w1t1, w1t2, w1t3,
      ew2, w2t1, w2t2, w2t3,
      obs, o1, o2, o3,
      dw1, d1t, dw2, d2t, rcnt);

  // encoder (bf16 3-split MFMA + fp64 drain => np-fp32-grade z)
  enc_mfma_kernel<true><<<dim3(BNR / 64, HIDD / 64), 256, 0, stream>>>(
      o1, o2, o3, w1t1, w1t2, w1t3, eb1, BNR, HIDD, OBSD,
      h1, h2, h3, nullptr, nullptr, nullptr);
  enc_mfma_kernel<false><<<dim3(BNR / 64, ZD / 64), 256, 0, stream>>>(
      h1, h2, h3, w2t1, w2t2, w2t3, eb2, BNR, ZD, HIDD,
      nullptr, nullptr, nullptr, out_z, zhi, zlo);

  dist_kernel<<<dim3(ZR / 512, NCHUNK), 1024, 0, stream>>>(
      zhi, zlo, chi, bcol, pb2, pidx);
  merge_kernel<<<ZR / 256, 256, 0, stream>>>(pb2, pidx, tokens, rcnt, rrows);
  rescue_kernel<<<512, 512, 0, stream>>>(rcnt, rrows, out_z, cbT, bcold, tokens);
  gather_kernel<<<(ZR * 16) / 256, 256, 0, stream>>>(tokens, cb, out_zq, zqb);

  // decoder (bf16 1-pass MFMA)
  dec_mfma_kernel<true, true><<<dim3(BNR / 64, HIDD / 64), 256, 0, stream>>>(
      zqb, d1t, db1, BNR, HIDD, ZD, hdec, nullptr);
  dec_mfma_kernel<false, false><<<dim3(BNR / 64, OBSD / 64), 256, 0, stream>>>(
      hdec, d2t, db2, BNR, OBSD, HIDD, nullptr, out_rec);
}

// Round 10
// 220.208 us; speedup vs baseline: 2.0061x; 1.3379x over previous
//
#include <hip/hip_runtime.h>
#include <math.h>

#define VOCAB 4096
#define EMBED 64
#define OBSD  128
#define HIDD  512
#define BNR   4096        // batch rows (1024*4)
#define ZR    65536       // token rows (BNR*16)
#define ZD    1024        // 16*EMBED
#define NCHUNK 4
#define CHSZ  (VOCAB / NCHUNK)   // 1024 codes per chunk
#define TCODES 64                // codes per LDS tile
#define NTILES (CHSZ / TCODES)   // 16 tiles per chunk

// dist computes z-split scores (zhi+zlo vs unsplit c): ε = |z·Δc| ≈ 3.5e-4 rms
// scaled. Margin 4e-3 ≈ 7σ of gap noise; rows with approx top-2 gap < margin
// get an exact fp64 rescan (rescue v2, batched). Proven r9.
#define MARGIN_SCALED 4.0e-3f

// dist LDS layout strides (halfs), padded (proven r5-r9)
#define SSTR 136
#define GSTR (8 * SSTR)          // 1088 halfs per 16-code group
#define TYPSZ (4 * GSTR)         // 4352 halfs per tile buffer (hi only)

#define RB 8                     // rescue rows per batch

typedef _Float16 half8  __attribute__((ext_vector_type(8)));
typedef _Float16 half4  __attribute__((ext_vector_type(4)));
typedef short    bf16x8 __attribute__((ext_vector_type(8)));
typedef float    f32x4  __attribute__((ext_vector_type(4)));

__device__ __forceinline__ f32x4 mfma_f16(half8 a, half8 b, f32x4 c){
  return __builtin_amdgcn_mfma_f32_16x16x32_f16(a,b,c,0,0,0);
}
__device__ __forceinline__ f32x4 mfma_bf(bf16x8 a, bf16x8 b, f32x4 c){
  return __builtin_amdgcn_mfma_f32_16x16x32_bf16(a,b,c,0,0,0);
}
__device__ __forceinline__ unsigned short f2bf(float f){
  union{float f; unsigned u;} x; x.f=f;
  unsigned u = x.u + 0x7fffu + ((x.u>>16)&1u);
  return (unsigned short)(u>>16);
}
__device__ __forceinline__ float bf2f(unsigned short h){
  union{unsigned u; float f;} x; x.u = ((unsigned)h)<<16; return x.f;
}
__device__ __forceinline__ void split3(float w, unsigned short& b1,
                                       unsigned short& b2, unsigned short& b3){
  b1 = f2bf(w); float r  = w - bf2f(b1);
  b2 = f2bf(r); float r2 = r - bf2f(b2);
  b3 = f2bf(r2);
}
__device__ __forceinline__ bf16x8 ldbf(const unsigned short* p){
  return *(const bf16x8*)(const void*)p;
}

// ---------- fused prep: cb f16 + cbT + fp64 bias + weight splits + rcnt zero
__global__ __launch_bounds__(256) void prep_all_kernel(
    const float* __restrict__ cb, _Float16* __restrict__ chi,
    float* __restrict__ bcol, double* __restrict__ bcold,
    float* __restrict__ cbT,
    const float* __restrict__ ew1, unsigned short* __restrict__ w1t1,
    unsigned short* __restrict__ w1t2, unsigned short* __restrict__ w1t3,
    const float* __restrict__ ew2, unsigned short* __restrict__ w2t1,
    unsigned short* __restrict__ w2t2, unsigned short* __restrict__ w2t3,
    const float* __restrict__ obs, unsigned short* __restrict__ o1,
    unsigned short* __restrict__ o2, unsigned short* __restrict__ o3,
    const float* __restrict__ dw1, unsigned short* __restrict__ d1t,
    const float* __restrict__ dw2, unsigned short* __restrict__ d2t,
    int* __restrict__ rcnt)
{
  const int b = blockIdx.x;
  const int t = threadIdx.x;
  if (b == 0 && t == 0) *rcnt = 0;
  if (b < 16) {
    int j = b * 256 + t;
    double s = 0.0;
    #pragma unroll 8
    for (int d = 0; d < EMBED; ++d) {
      float c = cb[j * EMBED + d];
      s += (double)c * (double)c;
      chi[j * EMBED + d] = (_Float16)(c * 4096.0f);   // pow2 scale exact
      cbT[(size_t)d * VOCAB + j] = c;                 // coalesced write
    }
    double bd = -0.5 * s * 4096.0;
    bcold[j] = bd;
    bcol[j] = (float)bd;
  } else if (b < 272) {
    // ew1 [OBSD][HIDD] -> 3-split [HIDD][OBSD]
    int e = (b - 16) * 256 + t;
    int n = e / OBSD, k = e % OBSD;
    split3(ew1[(size_t)k * HIDD + n], w1t1[e], w1t2[e], w1t3[e]);
  } else if (b < 2320) {
    // ew2 [HIDD][ZD] -> 3-split [ZD][HIDD]
    int e = (b - 272) * 256 + t;
    int n = e / HIDD, k = e % HIDD;
    split3(ew2[(size_t)k * ZD + n], w2t1[e], w2t2[e], w2t3[e]);
  } else if (b < 4368) {
    // obs elementwise 3-split
    int e = (b - 2320) * 256 + t;
    split3(obs[e], o1[e], o2[e], o3[e]);
  } else if (b < 6416) {
    // dw1 [ZD][HIDD] -> bf16 [HIDD][ZD]
    int e = (b - 4368) * 256 + t;
    int n = e / ZD, k = e % ZD;
    d1t[e] = f2bf(dw1[(size_t)k * HIDD + n]);
  } else {
    // dw2 [HIDD][OBSD] -> bf16 [OBSD][HIDD]
    int e = (b - 6416) * 256 + t;
    int n = e / HIDD, k = e % HIDD;
    d2t[e] = f2bf(dw2[(size_t)k * OBSD + n]);
  }
}

// ---------- LDS-staged GEMM template (enc1/enc2/dec1). r9 post-mortem: the
// 64x64 direct-from-global MFMA kernel is L1-miss-path-bound (~3 MB/CU, both
// pipes <13% busy). Here: tile BM x 128, 8 waves (2m x 4n), BK=32, single LDS
// buffer with issue-early/write-late (r5/r7-proven), padded row stride 40
// halfs (80 B: conflict-free for b128 reads AND 16B-aligned).
// NSPLIT=3: bf16 3-split, 6-MFMA chain + per-step fp64 drain (order-identical
// to r9's enc => bitwise-equal z/h). NSPLIT=1: plain bf16 C-in chain (dec1).
// OUT: 0 = relu+split3(H1..H3), 1 = Z + f16 hi/lo (Zhi,Zlo), 2 = relu+bf16(H1)
template<int NSPLIT, int MS, bool RELU, int OUT>
__global__ __launch_bounds__(512) void gemm_lds_kernel(
    const unsigned short* __restrict__ A1, const unsigned short* __restrict__ A2,
    const unsigned short* __restrict__ A3,
    const unsigned short* __restrict__ B1, const unsigned short* __restrict__ B2,
    const unsigned short* __restrict__ B3,
    const float* __restrict__ bias, int M, int N, int K,
    unsigned short* __restrict__ H1, unsigned short* __restrict__ H2,
    unsigned short* __restrict__ H3,
    float* __restrict__ Z, _Float16* __restrict__ Zhi, _Float16* __restrict__ Zlo)
{
  constexpr int BM  = MS * 32;
  constexpr int ASZ = BM * 40;          // halfs per A split
  constexpr int BSZ = 128 * 40;         // halfs per B split
  constexpr int ACH = BM * 4;           // 16B chunks per A split
  constexpr int TCH = ACH + 512;        // + B chunks (128*4)
  __shared__ unsigned short lds[NSPLIT * (ASZ + BSZ)];

  const int tid  = threadIdx.x;
  const int wave = tid >> 6;
  const int lane = tid & 63;
  const int l15  = lane & 15;
  const int lg   = lane >> 4;
  const int wm   = wave >> 2;           // 0..1
  const int wn   = wave & 3;            // 0..3
  const int m0   = blockIdx.x * BM;
  const int n0   = blockIdx.y * 128;

  const unsigned short* Aps[3] = {A1, A2, A3};
  const unsigned short* Bps[3] = {B1, B2, B3};

  // staging slots: thread handles chunks {tid, tid+512} of the (A|B) space
  size_t goff[2]; int lb[2], pst[2]; bool valid[2], isA[2];
  #pragma unroll
  for (int sl = 0; sl < 2; ++sl) {
    int c = tid + sl * 512;
    valid[sl] = c < TCH;
    bool a = c < ACH;
    isA[sl] = a;
    int cr = a ? c : (c - ACH);
    if (!valid[sl]) cr = 0;
    int row = cr >> 2, o16 = cr & 3;
    goff[sl] = (size_t)(a ? m0 + row : n0 + row) * K + o16 * 8;
    lb[sl]   = (a ? 0 : NSPLIT * ASZ) + row * 40 + o16 * 8;
    pst[sl]  = a ? ASZ : BSZ;
  }

  // prologue: stage k-step 0
  #pragma unroll
  for (int sl = 0; sl < 2; ++sl) if (valid[sl]) {
    #pragma unroll
    for (int p = 0; p < NSPLIT; ++p)
      *(bf16x8*)(void*)&lds[lb[sl] + p * pst[sl]] =
          ldbf((isA[sl] ? Aps[p] : Bps[p]) + goff[sl]);
  }
  __syncthreads();

  double accd[MS][2][4];
  f32x4  accf[MS][2];
  #pragma unroll
  for (int ms = 0; ms < MS; ++ms)
    #pragma unroll
    for (int ns = 0; ns < 2; ++ns) {
      accf[ms][ns] = (f32x4){0.f, 0.f, 0.f, 0.f};
      #pragma unroll
      for (int r = 0; r < 4; ++r) accd[ms][ns][r] = 0.0;
    }

  const int KS = K / 32;
  for (int step = 0; step < KS; ++step) {
    bf16x8 nv[NSPLIT][2];
    const bool pre = (step + 1 < KS);
    if (pre) {
      #pragma unroll
      for (int sl = 0; sl < 2; ++sl) if (valid[sl]) {
        #pragma unroll
        for (int p = 0; p < NSPLIT; ++p)
          nv[p][sl] = ldbf((isA[sl] ? Aps[p] : Bps[p]) + goff[sl]
                           + (size_t)(step + 1) * 32);
      }
    }

    bf16x8 af[NSPLIT][MS], bfr[NSPLIT][2];
    #pragma unroll
    for (int ms = 0; ms < MS; ++ms) {
      const int ar = (wm * MS * 16 + ms * 16 + l15) * 40 + lg * 8;
      #pragma unroll
      for (int p = 0; p < NSPLIT; ++p)
        af[p][ms] = *(const bf16x8*)(const void*)&lds[p * ASZ + ar];
    }
    #pragma unroll
    for (int ns = 0; ns < 2; ++ns) {
      const int br = (wn * 32 + ns * 16 + l15) * 40 + lg * 8;
      #pragma unroll
      for (int p = 0; p < NSPLIT; ++p)
        bfr[p][ns] = *(const bf16x8*)(const void*)&lds[NSPLIT * ASZ + p * BSZ + br];
    }

    #pragma unroll
    for (int ms = 0; ms < MS; ++ms)
      #pragma unroll
      for (int ns = 0; ns < 2; ++ns) {
        if constexpr (NSPLIT == 3) {
          f32x4 acc = {0.f, 0.f, 0.f, 0.f};
          // smallest terms first, dominant a1*b1 last (order == r9 enc)
          acc = mfma_bf(af[0][ms], bfr[2][ns], acc);
          acc = mfma_bf(af[1][ms], bfr[1][ns], acc);
          acc = mfma_bf(af[2][ms], bfr[0][ns], acc);
          acc = mfma_bf(af[0][ms], bfr[1][ns], acc);
          acc = mfma_bf(af[1][ms], bfr[0][ns], acc);
          acc = mfma_bf(af[0][ms], bfr[0][ns], acc);
          #pragma unroll
          for (int r = 0; r < 4; ++r) accd[ms][ns][r] += (double)acc[r];
        } else {
          accf[ms][ns] = mfma_bf(af[0][ms], bfr[0][ns], accf[ms][ns]);
        }
      }

    __syncthreads();              // all waves done reading lds
    if (pre) {
      #pragma unroll
      for (int sl = 0; sl < 2; ++sl) if (valid[sl]) {
        #pragma unroll
        for (int p = 0; p < NSPLIT; ++p)
          *(bf16x8*)(void*)&lds[lb[sl] + p * pst[sl]] = nv[p][sl];
      }
    }
    __syncthreads();              // next step visible
  }

  #pragma unroll
  for (int ms = 0; ms < MS; ++ms)
    #pragma unroll
    for (int ns = 0; ns < 2; ++ns)
      #pragma unroll
      for (int r = 0; r < 4; ++r) {
        int row = m0 + wm * MS * 16 + ms * 16 + lg * 4 + r;
        int col = n0 + wn * 32 + ns * 16 + l15;
        float v = (NSPLIT == 3 ? (float)accd[ms][ns][r] : accf[ms][ns][r])
                  + bias[col];
        if constexpr (RELU) v = v > 0.f ? v : 0.f;
        size_t o = (size_t)row * N + col;
        if constexpr (OUT == 0) {
          split3(v, H1[o], H2[o], H3[o]);
        } else if constexpr (OUT == 1) {
          Z[o] = v;
          _Float16 hi = (_Float16)v;
          Zhi[o] = hi;
          Zlo[o] = (_Float16)(v - (float)hi);
        } else {
          H1[o] = f2bf(v);
        }
      }
}

// ---------- dec2 GEMM: plain bf16 1-pass MFMA, direct loads (small: ~10 µs)
template<bool RELU, bool OUTBF>
__global__ __launch_bounds__(256) void dec_mfma_kernel(
    const unsigned short* __restrict__ A, const unsigned short* __restrict__ B,
    const float* __restrict__ bias, int M, int N, int K,
    unsigned short* __restrict__ Obf, float* __restrict__ Of)
{
  const int tid  = threadIdx.x;
  const int wave = tid >> 6;
  const int lane = tid & 63;
  const int l15  = lane & 15;
  const int lg   = lane >> 4;
  const int m0 = blockIdx.x * 64 + (wave >> 1) * 32;
  const int n0 = blockIdx.y * 64 + (wave & 1) * 32;

  f32x4 acc[2][2] = {};
  for (int k0 = 0; k0 < K; k0 += 32) {
    bf16x8 a[2], b[2];
    #pragma unroll
    for (int ms = 0; ms < 2; ++ms)
      a[ms] = ldbf(A + (size_t)(m0 + ms * 16 + l15) * K + k0 + lg * 8);
    #pragma unroll
    for (int ns = 0; ns < 2; ++ns)
      b[ns] = ldbf(B + (size_t)(n0 + ns * 16 + l15) * K + k0 + lg * 8);
    #pragma unroll
    for (int ms = 0; ms < 2; ++ms)
      #pragma unroll
      for (int ns = 0; ns < 2; ++ns)
        acc[ms][ns] = mfma_bf(a[ms], b[ns], acc[ms][ns]);
  }
  #pragma unroll
  for (int ms = 0; ms < 2; ++ms)
    #pragma unroll
    for (int ns = 0; ns < 2; ++ns)
      #pragma unroll
      for (int r = 0; r < 4; ++r) {
        int row = m0 + ms * 16 + lg * 4 + r;
        int col = n0 + ns * 16 + l15;
        float v = acc[ms][ns][r] + bias[col];
        if constexpr (RELU) v = v > 0.f ? v : 0.f;
        if constexpr (OUTBF) Obf[(size_t)row * N + col] = f2bf(v);
        else                 Of[(size_t)row * N + col] = v;
      }
}

// ---------- VQ distance: z-split (zhi+zlo) vs unsplit c — 4-MFMA chain.
// Chunked, LDS-staged codebook, 16 waves/block. Proven r9.
// NOTE: no min-waves clause — a VGPR cap makes the compiler demote the
// loop-invariant z fragments to per-iteration reloads (r3: 2 GB HBM, 3x slower).
__global__ __launch_bounds__(1024) void dist_kernel(
    const _Float16* __restrict__ zhi, const _Float16* __restrict__ zlo,
    const _Float16* __restrict__ chi, const float* __restrict__ bcol,
    float2* __restrict__ pb2, int* __restrict__ pidx)
{
  __shared__ _Float16 sh[2][TYPSZ];      // [buf][padded 64-code tile]
  __shared__ float    sbc[CHSZ];

  const int tid  = threadIdx.x;
  const int wave = tid >> 6;
  const int lane = tid & 63;
  const int l15  = lane & 15;
  const int lg   = lane >> 4;
  const int rowW = blockIdx.x * 512 + wave * 32;
  const int ch   = blockIdx.y;

  half8 ah0[2], ah1[2], al0[2], al1[2];
  #pragma unroll
  for (int s = 0; s < 2; ++s) {
    const size_t base = (size_t)(rowW + s * 16 + l15) * EMBED + lg * 8;
    ah0[s] = *(const half8*)(zhi + base);
    ah1[s] = *(const half8*)(zhi + base + 32);
    al0[s] = *(const half8*)(zlo + base);
    al1[s] = *(const half8*)(zlo + base + 32);
  }

  const _Float16* gsrc = chi + (size_t)ch * CHSZ * EMBED;
  const int code = tid >> 4, rem = tid & 15, sl = rem >> 1, hf = rem & 1;
  const int ld = (code >> 4) * GSTR + sl * SSTR + (code & 15) * 8 + hf * 4;
  const size_t goff = (size_t)code * EMBED + sl * 8 + hf * 4;

  sbc[tid] = bcol[ch * CHSZ + tid];

  *(half4*)(&sh[0][ld]) = *(const half4*)(gsrc + goff);
  __syncthreads();

  float best[2][4], second[2][4];
  int   bidx[2][4];
  #pragma unroll
  for (int s = 0; s < 2; ++s)
    #pragma unroll
    for (int r = 0; r < 4; ++r) {
      best[s][r] = -INFINITY; second[s][r] = -INFINITY; bidx[s][r] = 0;
    }

  for (int tile = 0; tile < NTILES; ++tile) {
    const int buf = tile & 1;
    half4 v0 = {};
    if (tile + 1 < NTILES)
      v0 = *(const half4*)(gsrc + (size_t)(tile + 1) * (TCODES * EMBED) + goff);

    const _Float16* ph = &sh[buf][0];
    #pragma unroll
    for (int grp = 0; grp < 4; ++grp) {
      const int rb = grp * GSTR + l15 * 8;
      half8 bh0 = *(const half8*)(ph + rb + lg * SSTR);
      half8 bh1 = *(const half8*)(ph + rb + (4 + lg) * SSTR);
      const int cloc = tile * TCODES + grp * 16 + l15;
      const int col  = ch * CHSZ + cloc;
      const float vb = sbc[cloc];
      const f32x4 seed = {vb, vb, vb, vb};
      #pragma unroll
      for (int s = 0; s < 2; ++s) {
        f32x4 acc = seed;
        acc = mfma_f16(al0[s], bh0, acc);
        acc = mfma_f16(al1[s], bh1, acc);
        acc = mfma_f16(ah0[s], bh0, acc);
        acc = mfma_f16(ah1[s], bh1, acc);
        #pragma unroll
        for (int r = 0; r < 4; ++r) {
          float v = acc[r];
          float sn = __builtin_amdgcn_fmed3f(second[s][r], best[s][r], v);
          bool gt = v > best[s][r];
          best[s][r] = gt ? v : best[s][r];
          bidx[s][r] = gt ? col : bidx[s][r];
          second[s][r] = sn;
        }
      }
    }
    __syncthreads();
    if (tile + 1 < NTILES)
      *(half4*)(&sh[buf ^ 1][ld]) = v0;
    __syncthreads();
  }

  #pragma unroll
  for (int m = 1; m <= 8; m <<= 1) {
    #pragma unroll
    for (int s = 0; s < 2; ++s)
      #pragma unroll
      for (int r = 0; r < 4; ++r) {
        float ob = __shfl_xor(best[s][r], m, 64);
        float os = __shfl_xor(second[s][r], m, 64);
        int   oi = __shfl_xor(bidx[s][r], m, 64);
        float mn = fminf(best[s][r], ob);
        second[s][r] = fmaxf(mn, fmaxf(second[s][r], os));
        if (ob > best[s][r]) { best[s][r] = ob; bidx[s][r] = oi; }
      }
  }

  if (l15 == 0) {
    #pragma unroll
    for (int s = 0; s < 2; ++s)
      #pragma unroll
      for (int r = 0; r < 4; ++r) {
        int row = rowW + s * 16 + lg * 4 + r;
        pb2 [(size_t)ch * ZR + row] = make_float2(best[s][r], second[s][r]);
        pidx[(size_t)ch * ZR + row] = bidx[s][r];
      }
  }
}

// ---------- merge chunk partials -> tokens + rescue list
__global__ __launch_bounds__(256) void merge_kernel(
    const float2* __restrict__ pb2, const int* __restrict__ pidx,
    int* __restrict__ tokens, int* __restrict__ rcnt, int* __restrict__ rrows)
{
  int r = blockIdx.x * 256 + threadIdx.x;
  float b = -INFINITY, s = -INFINITY;
  int bi = 0;
  #pragma unroll
  for (int c = 0; c < NCHUNK; ++c) {
    float2 p = pb2[(size_t)c * ZR + r];
    int    i = pidx[(size_t)c * ZR + r];
    if (p.x > b) { s = fmaxf(b, p.y); b = p.x; bi = i; }
    else         { s = fmaxf(s, p.x); }
  }
  tokens[r] = bi;
  if (b - s < MARGIN_SCALED) {
    int p = atomicAdd(rcnt, 1);
    if (p < ZR) rrows[p] = r;
  }
}

// ---------- rescue v2: exact fp64 rescan, batched (proven r9)
__global__ __launch_bounds__(512) void rescue_kernel(
    const int* __restrict__ cnt, const int* __restrict__ rows,
    const float* __restrict__ z, const float* __restrict__ cbT,
    const double* __restrict__ bcold, int* __restrict__ tokens)
{
  __shared__ double zl[RB][EMBED];
  __shared__ int    ridx[RB];
  __shared__ double swv[8][RB];
  __shared__ int    swi[8][RB];

  int n = *cnt; if (n > ZR) n = ZR;
  int nb = (n + RB - 1) / RB;
  const int tid = threadIdx.x;

  for (int batch = blockIdx.x; batch < nb; batch += gridDim.x) {
    __syncthreads();
    if (tid < RB) {
      int e = batch * RB + tid;
      ridx[tid] = (e < n) ? rows[e] : -1;
    }
    __syncthreads();
    {
      int r = tid >> 6, k = tid & 63;
      int rr = ridx[r];
      zl[r][k] = (rr >= 0) ? (double)z[(size_t)rr * EMBED + k] : 0.0;
    }
    __syncthreads();

    double best[RB]; int bidx[RB];
    #pragma unroll
    for (int r = 0; r < RB; ++r) { best[r] = -1.0e300; bidx[r] = 0; }

    for (int c = 0; c < VOCAB / 512; ++c) {
      const int j = c * 512 + tid;
      double acc[RB] = {};
      #pragma unroll 16
      for (int k = 0; k < EMBED; ++k) {
        double cd = (double)cbT[(size_t)k * VOCAB + j];
        #pragma unroll
        for (int r = 0; r < RB; ++r)
          acc[r] = fma(cd, zl[r][k], acc[r]);
      }
      const double bc = bcold[j];
      #pragma unroll
      for (int r = 0; r < RB; ++r) {
        double s = 4096.0 * acc[r] + bc;
        if (s > best[r]) { best[r] = s; bidx[r] = j; }
      }
    }

    #pragma unroll
    for (int m = 1; m < 64; m <<= 1) {
      #pragma unroll
      for (int r = 0; r < RB; ++r) {
        double ov = __shfl_xor(best[r], m, 64);
        int    oi = __shfl_xor(bidx[r], m, 64);
        if (ov > best[r] || (ov == best[r] && oi < bidx[r])) {
          best[r] = ov; bidx[r] = oi;
        }
      }
    }
    const int wv = tid >> 6, ln = tid & 63;
    if (ln == 0)
      #pragma unroll
      for (int r = 0; r < RB; ++r) { swv[wv][r] = best[r]; swi[wv][r] = bidx[r]; }
    __syncthreads();
    if (tid < RB) {
      int r = tid;
      double bv = swv[0][r]; int bi = swi[0][r];
      #pragma unroll
      for (int w2 = 1; w2 < 8; ++w2) {
        double ov = swv[w2][r]; int oi = swi[w2][r];
        if (ov > bv || (ov == bv && oi < bi)) { bv = ov; bi = oi; }
      }
      if (ridx[r] >= 0) tokens[ridx[r]] = bi;
    }
  }
}

// ---------- gather z_q: exact fp32 copy + bf16 copy for the decoder
__global__ __launch_bounds__(256) void gather_kernel(
    const int* __restrict__ tokens, const float* __restrict__ cb,
    float* __restrict__ zq, unsigned short* __restrict__ zqb)
{
  int g = blockIdx.x * 256 + threadIdx.x;
  int row = g >> 4;
  int part = g & 15;
  int tok = tokens[row];
  float4 cv = ((const float4*)cb)[tok * 16 + part];
  ((float4*)zq)[g] = cv;
  ushort4 o;
  o.x = f2bf(cv.x); o.y = f2bf(cv.y); o.z = f2bf(cv.z); o.w = f2bf(cv.w);
  ((ushort4*)zqb)[g] = o;
}

extern "C" void kernel_launch(void* const* d_in, const int* in_sizes, int n_in,
                              void* d_out, int out_size, void* d_ws, size_t ws_size,
                              hipStream_t stream)
{
  const float* obs = (const float*)d_in[0];
  const float* ew1 = (const float*)d_in[1];
  const float* eb1 = (const float*)d_in[2];
  const float* ew2 = (const float*)d_in[3];
  const float* eb2 = (const float*)d_in[4];
  const float* dw1 = (const float*)d_in[5];
  const float* db1 = (const float*)d_in[6];
  const float* dw2 = (const float*)d_in[7];
  const float* db2 = (const float*)d_in[8];
  const float* cb  = (const float*)d_in[9];

  float* out_z   = (float*)d_out;                    // [65536][64]
  float* out_zq  = out_z + (size_t)ZR * EMBED;       // [65536][64]
  float* out_rec = out_z + 2 * (size_t)ZR * EMBED;   // [4096][128]

  // h 3-split (3 x 4MB) staged in the (dead-until-gather) out_zq slot
  unsigned short* h1 = (unsigned short*)out_zq;
  unsigned short* h2 = h1 + (size_t)BNR * HIDD;
  unsigned short* h3 = h2 + (size_t)BNR * HIDD;

  char* w = (char*)d_ws;
  _Float16* chi  = (_Float16*)w; w += (size_t)VOCAB * EMBED * 2;  // 512 KB
  float*    bcol = (float*)w;    w += 64 * 1024;                  // 16 KB used
  double*   bcold = (double*)w;  w += 64 * 1024;                  // 32 KB used
  float*    cbT  = (float*)w;    w += (size_t)VOCAB * EMBED * 4;  // 1 MB
  _Float16* zhi  = (_Float16*)w; w += (size_t)ZR * EMBED * 2;     // 8 MB
  _Float16* zlo  = (_Float16*)w; w += (size_t)ZR * EMBED * 2;     // 8 MB
  unsigned short* w1t1 = (unsigned short*)w; w += (size_t)HIDD * OBSD * 2;
  unsigned short* w1t2 = (unsigned short*)w; w += (size_t)HIDD * OBSD * 2;
  unsigned short* w1t3 = (unsigned short*)w; w += (size_t)HIDD * OBSD * 2;
  unsigned short* w2t1 = (unsigned short*)w; w += (size_t)ZD * HIDD * 2;
  unsigned short* w2t2 = (unsigned short*)w; w += (size_t)ZD * HIDD * 2;
  unsigned short* w2t3 = (unsigned short*)w; w += (size_t)ZD * HIDD * 2;
  unsigned short* d1t  = (unsigned short*)w; w += (size_t)HIDD * ZD * 2;
  unsigned short* d2t  = (unsigned short*)w; w += (size_t)OBSD * HIDD * 2;
  int* tokens = (int*)w;  w += (size_t)ZR * 4;
  int* rrows  = (int*)w;  w += (size_t)ZR * 4;
  int* rcnt   = (int*)w;  w += 64;
  float2* pb2 = (float2*)w; w += (size_t)NCHUNK * ZR * 8;         // 2 MB
  int*   pidx = (int*)w;    w += (size_t)NCHUNK * ZR * 4;         // 1 MB

  // overlays (dead-time disjoint):
  unsigned short* o1 = (unsigned short*)zhi;           // [prep..enc1]
  unsigned short* o2 = o1 + (size_t)BNR * OBSD;
  unsigned short* o3 = o2 + (size_t)BNR * OBSD;
  unsigned short* zqb  = (unsigned short*)zhi;         // [gather..dec1]
  unsigned short* hdec = (unsigned short*)zlo;         // [dec1..dec2]

  prep_all_kernel<<<6672, 256, 0, stream>>>(
      cb, chi, bcol, bcold, cbT,
      ew1, w1t1, w1t2, w1t3,
      ew2, w2t1, w2t2, w2t3,
      obs, o1, o2, o3,
      dw1, d1t, dw2, d2t, rcnt);

  // enc1: 3-split, tile 64x128, relu + h-split3
  gemm_lds_kernel<3, 2, true, 0><<<dim3(BNR / 64, HIDD / 128), 512, 0, stream>>>(
      o1, o2, o3, w1t1, w1t2, w1t3, eb1, BNR, HIDD, OBSD,
      h1, h2, h3, nullptr, nullptr, nullptr);
  // enc2: 3-split, tile 128x128, z + f16 hi/lo
  gemm_lds_kernel<3, 4, false, 1><<<dim3(BNR / 128, ZD / 128), 512, 0, stream>>>(
      h1, h2, h3, w2t1, w2t2, w2t3, eb2, BNR, ZD, HIDD,
      nullptr, nullptr, nullptr, out_z, zhi, zlo);

  dist_kernel<<<dim3(ZR / 512, NCHUNK), 1024, 0, stream>>>(
      zhi, zlo, chi, bcol, pb2, pidx);
  merge_kernel<<<ZR / 256, 256, 0, stream>>>(pb2, pidx, tokens, rcnt, rrows);
  rescue_kernel<<<512, 512, 0, stream>>>(rcnt, rrows, out_z, cbT, bcold, tokens);
  gather_kernel<<<(ZR * 16) / 256, 256, 0, stream>>>(tokens, cb, out_zq, zqb);

  // dec1: plain bf16, tile 64x128, relu + bf16 out
  gemm_lds_kernel<1, 2, true, 2><<<dim3(BNR / 64, HIDD / 128), 512, 0, stream>>>(
      zqb, zqb, zqb, d1t, d1t, d1t, db1, BNR, HIDD, ZD,
      hdec, nullptr, nullptr, nullptr, nullptr, nullptr);
  // dec2: small, direct-load kernel
  dec_mfma_kernel<false, false><<<dim3(BNR / 64, OBSD / 64), 256, 0, stream>>>(
      hdec, d2t, db2, BNR, OBSD, HIDD, nullptr, out_rec);
}